// Round 16
// baseline (212.461 us; speedup 1.0000x reference)
//
#include <hip/hip_runtime.h>

typedef unsigned int u32;
typedef unsigned short u16;

#define NT 256
#define NBLK 2500

typedef __attribute__((ext_vector_type(8))) short bh8;
typedef __attribute__((ext_vector_type(4))) float f4;
union U8 { uint4 u; bh8 h; };

__device__ __forceinline__ u16 fb(float x){            // fp32->bf16 RNE (used by prep)
    u32 u = __float_as_uint(x);
    u += 0x7fffu + ((u>>16)&1u);
    return (u16)(u>>16);
}
// pack two f32 -> two bf16 in one VALU op (RNE, same as fb): lo=a, hi=b
__device__ __forceinline__ u32 pk2(float a, float b){
    u32 r;
    __asm__("v_cvt_pk_bf16_f32 %0, %1, %2" : "=v"(r) : "v"(a), "v"(b));
    return r;
}
__device__ __forceinline__ float bf_lo(u32 w){ return __uint_as_float(w<<16); }
__device__ __forceinline__ float bf_hi(u32 w){ return __uint_as_float(w & 0xffff0000u); }

// tanh-form gelu (R7/R8 verified): ~10 VALU + 2 trans; deviation from
// erf-form <= ~4e-4, under the bf16 quantization applied right after.
__device__ __forceinline__ float gelu(float x){
    float x2 = x*x;
    float y  = x * fmaf(0.0356774081f, x2, 0.7978845608f);  // sqrt(2/pi)(x+0.044715x^3)
    float t  = __expf(-2.0f * fabsf(y));                    // e^{-2|y|}
    float r  = __builtin_amdgcn_rcpf(1.0f + t);             // raw v_rcp_f32 (~1ulp)
    float m  = t * r;
    float th = fmaf(-2.0f, m, 1.0f);                        // tanh(|y|)
    float hx = 0.5f * x;
    return fmaf(fabsf(hx), th, hx);                         // 0.5x + 0.5|x|tanh(|y|)
}

// ---------- prep: pack W1^T / W2^T (k and v) into MFMA A-frag order, bf16 ----
// ws16 layout (u16): [A1K:2048][A1V:2048][A2K:16384][A2V:16384]
__global__ void prep_pack(const float* __restrict__ kw1, const float* __restrict__ vw1,
                          const float* __restrict__ kw2, const float* __restrict__ vw2,
                          u16* __restrict__ ws16)
{
    int t = blockIdx.x*256 + threadIdx.x;        // 0..36863
    if (t >= 36864) return;
    float val;
    if (t < 4096){
        const float* w1 = (t < 2048) ? kw1 : vw1;
        int u = t & 2047;
        int mt = u >> 9, lane = (u>>3)&63, j = u&7;
        int m = mt*16 + (lane&15);
        int x = (lane>>4)*8 + j;
        val = w1[x*64 + m];
    } else {
        int s2 = t - 4096;
        const float* w2 = (s2 < 16384) ? kw2 : vw2;
        int u = s2 & 16383;
        int blkidx = u >> 9;                      // mt*2+s
        int mt = blkidx >> 1, s = blkidx & 1;
        int lane = (u>>3)&63, j = u&7;
        int ij = mt*16 + (lane&15);
        int c  = s*32 + (lane>>4)*8 + j;
        val = w2[c*256 + ij];
    }
    ws16[t] = fb(val);
}

// ---------- one radial conv via MFMA: t2[16] stays in registers ------------
// BYTE-IDENTICAL to R15's verified conv (edge tiles in 2 PAIRS nt=ntp*2+b,
// both staged via LDS h-bounce into disjoint 1152-u16 hT halves before one
// lgkm fence; A2/b2g read 2x; tm loads hoisted to entry). The caller now
// passes wc (edge-tile half, 0/1) as `w` and a per-wave 2304-u16 hT region.
// NOTE (R16 discovery): R1/R2's NT=256 wrong-results were an LDS bug — wave
// hT regions strided 1152 but each wave writes 2304 (b*1152+...), so waves
// overlapped. Fixed here with stride 2304.
// Invariants (round-5 + round-1 lessons):
//  - every loop indexing a register array MUST fully unroll;
//  - t2v is written UNCONDITIONALLY via selects (v_cndmask), never under a
//    divergent `if`.
__device__ __forceinline__ void conv_mfma(
    const u16* __restrict__ pA1, const u16* __restrict__ pA2,
    const float* __restrict__ b1g, const float* __restrict__ b2g,
    const bh8* __restrict__ B1f,          // [4] cached ef frags
    const u32* __restrict__ tmpS,         // stride 10 u32 rows (16 bf16)
    u16* __restrict__ hT,                 // this wave's H region: 2 tiles x 1152 u16
    float* __restrict__ t2v,              // [16] regs out
    int w, int lane)
{
    const int r = lane & 15, q = lane >> 4;

    #pragma unroll
    for (int mt=0; mt<16; ++mt) t2v[mt] = 0.f;

    // hoisted W1-bias rows
    float4 bva0 = *(const float4*)(b1g +  0 + q*4);
    float4 bva1 = *(const float4*)(b1g + 16 + q*4);
    float4 bva2 = *(const float4*)(b1g + 32 + q*4);
    float4 bva3 = *(const float4*)(b1g + 48 + q*4);

    // hoisted tm loads (all 4 edge tiles) — gated by the caller's barrier
    uint2 tpA = *(const uint2*)(tmpS + (((w*4+0)*16 + r)*10) + q*2);
    uint2 tpB = *(const uint2*)(tmpS + (((w*4+1)*16 + r)*10) + q*2);
    uint2 tpC = *(const uint2*)(tmpS + (((w*4+2)*16 + r)*10) + q*2);
    uint2 tpD = *(const uint2*)(tmpS + (((w*4+3)*16 + r)*10) + q*2);

    #pragma unroll
    for (int ntp=0; ntp<2; ++ntp){
        bh8 b2f0[2], b2f1[2];
        float tm[2][4];
        {
            uint2 t0 = (ntp==0) ? tpA : tpC;   // folds at compile time
            uint2 t1 = (ntp==0) ? tpB : tpD;
            tm[0][0]=bf_lo(t0.x); tm[0][1]=bf_hi(t0.x);
            tm[0][2]=bf_lo(t0.y); tm[0][3]=bf_hi(t0.y);
            tm[1][0]=bf_lo(t1.x); tm[1][1]=bf_hi(t1.x);
            tm[1][2]=bf_lo(t1.y); tm[1][3]=bf_hi(t1.y);
        }

        // ---- staging: both tiles of the pair -> disjoint hT halves ----
        #pragma unroll
        for (int b=0; b<2; ++b){
            const int nt = ntp*2 + b;
            #pragma unroll
            for (int mt=0; mt<4; ++mt){
                bh8 a1 = *(const bh8*)(pA1 + ((mt*64 + lane)<<3));
                f4 d1 = {0.f,0.f,0.f,0.f};
                d1 = __builtin_amdgcn_mfma_f32_16x16x32_bf16(a1, B1f[nt], d1, 0,0,0);
                float4 bv = (mt==0)?bva0:(mt==1)?bva1:(mt==2)?bva2:bva3;
                float g0 = gelu(d1[0]+bv.x), g1 = gelu(d1[1]+bv.y);
                float g2 = gelu(d1[2]+bv.z), g3 = gelu(d1[3]+bv.w);
                uint2 pk; pk.x = pk2(g0,g1); pk.y = pk2(g2,g3);
                *(uint2*)(hT + b*1152 + r*72 + mt*16 + q*4) = pk;
            }
        }
        // write -> cross-lane-read fence (same-wave, semantically required)
        __asm__ volatile("s_waitcnt lgkmcnt(0)" ::: "memory");
        #pragma unroll
        for (int b=0; b<2; ++b){
            b2f0[b] = *(const bh8*)(hT + b*1152 + r*72 +      q*8);   // chans q*8..+7
            b2f1[b] = *(const bh8*)(hT + b*1152 + r*72 + 32 + q*8);   // chans 32+q*8..+7
        }

        // ---- main: all 16 ij-tiles, both pair tiles inner ----
        #pragma unroll
        for (int mt=0; mt<16; ++mt){
            bh8 a2s0 = *(const bh8*)(pA2 + (((mt*2+0)*64 + lane)<<3));
            bh8 a2s1 = *(const bh8*)(pA2 + (((mt*2+1)*64 + lane)<<3));
            float4 bv = *(const float4*)(b2g + mt*16 + q*4);
            float pb0, pb1;
            {
                f4 acc = {0.f,0.f,0.f,0.f};
                acc = __builtin_amdgcn_mfma_f32_16x16x32_bf16(a2s0, b2f0[0], acc, 0,0,0);
                acc = __builtin_amdgcn_mfma_f32_16x16x32_bf16(a2s1, b2f1[0], acc, 0,0,0);
                float p = (acc[0]+bv.x)*tm[0][0] + (acc[1]+bv.y)*tm[0][1]
                        + (acc[2]+bv.z)*tm[0][2] + (acc[3]+bv.w)*tm[0][3];
                p += __shfl_xor(p, 16);
                p += __shfl_xor(p, 32);
                pb0 = p;
            }
            {
                f4 acc = {0.f,0.f,0.f,0.f};
                acc = __builtin_amdgcn_mfma_f32_16x16x32_bf16(a2s0, b2f0[1], acc, 0,0,0);
                acc = __builtin_amdgcn_mfma_f32_16x16x32_bf16(a2s1, b2f1[1], acc, 0,0,0);
                float p = (acc[0]+bv.x)*tm[1][0] + (acc[1]+bv.y)*tm[1][1]
                        + (acc[2]+bv.z)*tm[1][2] + (acc[3]+bv.w)*tm[1][3];
                p += __shfl_xor(p, 16);
                p += __shfl_xor(p, 32);
                pb1 = p;
            }
            // owner lane of edge tile (w*4+nt), row r is (q=nt, r); nt = ntp*2 + (q&1)
            float sel = (q & 1) ? pb1 : pb0;
            t2v[mt] = ((q >> 1) == ntp) ? sel : t2v[mt];
        }
    }
}

// ---------------- fused main kernel -------------------------------------------
// ROUND-16: K/V conv split ACROSS WAVES. NT=256, 4 waves; wave w = (kv=w>>1,
// wc=w&1) runs conv kv for edge-tile half wc. Per-wave serial chain HALVES
// (one conv instead of two back-to-back); K and V run concurrently. Unlike
// R6 (in-wave merge: VGPR/LDS blowup) conv state per wave is unchanged, and
// unlike R1/R2 (whose failure was the hT stride-1152 overlap bug, found in
// R16 analysis) each wave gets a full 2304-u16 hT region. Phase 0 and conv
// internals byte-identical to R15 (verified 94us). LDS 46112B -> 3 blocks/CU
// x 4 waves = 12 waves/CU potential (was 8).
__global__ __launch_bounds__(NT, 1) void eqattn_main(
    const float* __restrict__ bk1, const float* __restrict__ bk2,
    const float* __restrict__ bv1, const float* __restrict__ bv2,
    const float* __restrict__ efg, const float* __restrict__ fg,
    const float* __restrict__ qw,  const float* __restrict__ qb,
    const float* __restrict__ kb1, const float* __restrict__ kb2,
    const float* __restrict__ vb1, const float* __restrict__ vb2,
    const float* __restrict__ ow,  const float* __restrict__ ob,
    const int* __restrict__ nidx,  const u16* __restrict__ ws16,
    float* __restrict__ outg)
{
    __shared__ __align__(16) u32 sTmpK[1280];  // 5120: tmp-k bf16 rows (stride 10 u32) -> attn scratch
    __shared__ __align__(16) u32 sTmpV[1280];  // 5120: tmp-v bf16 rows
    __shared__ __align__(16) u32 sKS [2048];   // 8192: k rows 16 u32 (pair-swizzled)
    __shared__ __align__(16) u32 sVS [2048];   // 8192: v rows
    __shared__ __align__(16) u16 sHT [9216];   // 18432: per-wave H regions (4 waves x 2304) — R1 bug fixed
    __shared__ __align__(16) float sQ[264];    // 1056: q vectors [8][33]

    const int t    = threadIdx.x;
    const int lane = t & 63;
    const int w    = t >> 6;          // 0..3
    const int wc   = w & 1;           // edge-tile half (tiles wc*4..wc*4+3)
    const int kv   = w >> 1;          // 0 = K conv, 1 = V conv
    const int r    = lane & 15, q = lane >> 4;
    const int n0   = blockIdx.x * 8;

    const u16* pA1k = ws16;
    const u16* pA1v = ws16 + 2048;
    const u16* pA2k = ws16 + 4096;
    const u16* pA2v = ws16 + 20480;

    // ---- phase 0 (threads 0..127, code identical to R15): gather f[src],
    // compute BOTH tmpK and tmpV rows for edge t ----
    if (t < 128){
        int e   = blockIdx.x*128 + t;
        int src = nidx[e];
        const float4* fr = (const float4*)(fg + src*32);
        float fs[32];
        #pragma unroll
        for (int i=0;i<8;++i){
            float4 v = fr[i];
            fs[i*4]=v.x; fs[i*4+1]=v.y; fs[i*4+2]=v.z; fs[i*4+3]=v.w;
        }
        float4 ka = *(const float4*)(bk1+e*8), kbv = *(const float4*)(bk1+e*8+4);
        float4 va = *(const float4*)(bv1+e*8), vbv = *(const float4*)(bv1+e*8+4);
        float b1k[8] = {ka.x,ka.y,ka.z,ka.w,kbv.x,kbv.y,kbv.z,kbv.w};
        float b1v[8] = {va.x,va.y,va.z,va.w,vbv.x,vbv.y,vbv.z,vbv.w};
        float tk[16], tv[16];
        #pragma unroll
        for (int m=0;m<8;++m){
            float t0=0.f,t1=0.f,u0=0.f,u1=0.f;
            #pragma unroll
            for (int d=0;d<4;++d){
                float fv = fs[m*4+d];
                t0 += fv*b1k[d*2];  t1 += fv*b1k[d*2+1];
                u0 += fv*b1v[d*2];  u1 += fv*b1v[d*2+1];
            }
            tk[m*2]=t0; tk[m*2+1]=t1; tv[m*2]=u0; tv[m*2+1]=u1;
        }
        #pragma unroll
        for (int i=0;i<8;++i){
            sTmpK[t*10+i] = pk2(tk[i*2], tk[i*2+1]);
            sTmpV[t*10+i] = pk2(tv[i*2], tv[i*2+1]);
        }
    }

    // ---- q = eq_linear(f, q_w, q_b): 256 tasks == NT, single pass ----
    {
        int ln = t>>5, m=(t>>2)&7, d=t&3;
        const float* frow = fg + (n0+ln)*32;
        int rr = ((d>0)?8:0) + m;
        float acc = (d==0) ? qb[m] : 0.f;
        #pragma unroll
        for (int mm=0;mm<8;++mm) acc += qw[rr*8+mm]*frow[mm*4+d];
        sQ[ln*33 + m*4 + d] = acc;
    }

    // ---- B1 frags for this wave's 4 edge tiles (half wc) ----
    bh8 B1f[4];
    #pragma unroll
    for (int nt=0; nt<4; ++nt){
        int eg = blockIdx.x*128 + (wc*4+nt)*16 + r;
        float4 ea = *(const float4*)(efg + eg*32 + q*8);
        float4 eb = *(const float4*)(efg + eg*32 + q*8 + 4);
        U8 uu;
        uu.u.x = pk2(ea.x, ea.y); uu.u.y = pk2(ea.z, ea.w);
        uu.u.z = pk2(eb.x, eb.y); uu.u.w = pk2(eb.z, eb.w);
        B1f[nt] = uu.h;
    }

    // ---- per-wave conv selection (wave-uniform) ----
    const u16*  pA1 = kv ? pA1v : pA1k;
    const u16*  pA2 = kv ? pA2v : pA2k;
    const float* b1 = kv ? vb1  : kb1;
    const float* b2 = kv ? vb2  : kb2;
    const u32* tmpS = kv ? sTmpV : sTmpK;
    u32*        dst = kv ? sVS  : sKS;
    u16*         hT = sHT + w*2304;

    // epilogue coefficients for this wave's edge (issue early)
    const int   el  = wc*64 + lane;            // edge-in-block this thread owns
    const int   eo  = blockIdx.x*128 + el;
    const float* c2g = kv ? bv2 : bk2;
    float4 c0 = *(const float4*)(c2g + eo*8);
    float4 c1 = *(const float4*)(c2g + eo*8 + 4);

    // tmp producers (waves 0,1) -> consumers (all waves): real barrier
    __syncthreads();

    // ---- this wave's conv (K or V, half wc) ----
    float t2[16];
    conv_mfma(pA1, pA2, b1, b2, B1f, tmpS, hT, t2, wc, lane);
    {
        #pragma unroll
        for (int m=0;m<8;++m){
            float t20 = t2[2*m], t21 = t2[2*m+1];
            uint2 pk;
            pk.x = pk2(t20*c0.x + t21*c1.x, t20*c0.y + t21*c1.y);
            pk.y = pk2(t20*c0.z + t21*c1.z, t20*c0.w + t21*c1.w);
            *(uint2*)(dst + el*16 + ((m ^ (el&7))<<1)) = pk;
        }
    }
    __syncthreads();

    float* lg  = (float*)sTmpK + 264;  // [32][17] = 544 floats (tmp rows dead)
    float* aoS = (float*)sTmpK + 808;  // [8][33] = 264 floats (1072 <= 1280)

    // ---- logits: 512 tasks, 2 passes of 256 ----
    #pragma unroll 1
    for (int p=0;p<2;++p){
        int task = p*NT + t;
        int ln = task>>6, hh=(task>>4)&3, k=task&15;
        int row = ln*16 + k;
        const float* qr = sQ + ln*33 + hh*8;
        uint2 k0 = *(const uint2*)(sKS + row*16 + (((hh<<1)     ^ (row&7))<<1));
        uint2 k1 = *(const uint2*)(sKS + row*16 + ((((hh<<1)|1) ^ (row&7))<<1));
        float acc = qr[0]*bf_lo(k0.x)+qr[1]*bf_hi(k0.x)
                  + qr[2]*bf_lo(k0.y)+qr[3]*bf_hi(k0.y)
                  + qr[4]*bf_lo(k1.x)+qr[5]*bf_hi(k1.x)
                  + qr[6]*bf_lo(k1.y)+qr[7]*bf_hi(k1.y);
        lg[(ln*4+hh)*17 + k] = acc * 0.35355339059327373f;
    }
    __syncthreads();

    // ---- softmax over 16 neighbors: 128 lane-tasks (32 rows x 4 lanes) ----
    if (t < 128){
        int row = t >> 2, sub = t & 3;
        float* rp = lg + row*17 + sub*4;
        float a0=rp[0], a1=rp[1], a2=rp[2], a3=rp[3];
        float mx = fmaxf(fmaxf(a0,a1), fmaxf(a2,a3));
        mx = fmaxf(mx, __shfl_xor(mx, 1));
        mx = fmaxf(mx, __shfl_xor(mx, 2));
        float e0=__expf(a0-mx), e1=__expf(a1-mx);
        float e2=__expf(a2-mx), e3=__expf(a3-mx);
        float s = (e0+e1)+(e2+e3);
        s += __shfl_xor(s, 1);
        s += __shfl_xor(s, 2);
        float inv = __builtin_amdgcn_rcpf(s);
        // one Newton step to keep softmax normalization at fp32 accuracy
        inv = inv * (2.0f - s*inv);
        rp[0]=e0*inv; rp[1]=e1*inv; rp[2]=e2*inv; rp[3]=e3*inv;
    }
    __syncthreads();

    // ---- attention output: 256 tasks == NT, single pass ----
    {
        int ln = t>>5, comp = t&31, hh = comp>>3;
        const float* ar = lg + (ln*4+hh)*17;
        float acc=0.f;
        #pragma unroll
        for (int k=0;k<16;++k){
            int row = ln*16 + k;
            u32 wv = sVS[row*16 + (((comp>>2) ^ (row&7))<<1) + ((comp>>1)&1)];
            acc += ar[k] * ((comp&1) ? bf_hi(wv) : bf_lo(wv));
        }
        aoS[ln*33 + comp] = acc;
    }
    __syncthreads();

    // ---- final eq_linear(o_w, o_b) -> fp32 out: 256 tasks == NT ----
    {
        int ln = t>>5, m=(t>>2)&7, d=t&3;
        int rr = ((d>0)?8:0) + m;
        float acc = (d==0) ? ob[m] : 0.f;
        #pragma unroll
        for (int mm=0;mm<8;++mm) acc += ow[rr*8+mm]*aoS[ln*33 + mm*4 + d];
        outg[(n0+ln)*32 + m*4 + d] = acc;
    }
}

extern "C" void kernel_launch(void* const* d_in, const int* in_sizes, int n_in,
                              void* d_out, int out_size, void* d_ws, size_t ws_size,
                              hipStream_t stream)
{
    (void)in_sizes; (void)n_in; (void)out_size; (void)ws_size;
    const float* bk1 = (const float*)d_in[0];
    const float* bk2 = (const float*)d_in[1];
    const float* bv1 = (const float*)d_in[2];
    const float* bv2 = (const float*)d_in[3];
    const float* efg = (const float*)d_in[4];
    const float* fg  = (const float*)d_in[5];
    const float* qw  = (const float*)d_in[6];
    const float* qb  = (const float*)d_in[7];
    const float* kw1 = (const float*)d_in[8];
    const float* kb1 = (const float*)d_in[9];
    const float* kw2 = (const float*)d_in[10];
    const float* kb2 = (const float*)d_in[11];
    const float* vw1 = (const float*)d_in[12];
    const float* vb1 = (const float*)d_in[13];
    const float* vw2 = (const float*)d_in[14];
    const float* vb2 = (const float*)d_in[15];
    const float* ow  = (const float*)d_in[16];
    const float* ob  = (const float*)d_in[17];
    const int* nidx  = (const int*)d_in[18];
    u16* ws16 = (u16*)d_ws;

    prep_pack<<<144, 256, 0, stream>>>(kw1, vw1, kw2, vw2, ws16);
    eqattn_main<<<NBLK, NT, 0, stream>>>(
        bk1,bk2,bv1,bv2, efg, fg, qw,qb, kb1,kb2, vb1,vb2,
        ow,ob, nidx, ws16, (float*)d_out);
}

// Round 17
// 205.348 us; speedup vs baseline: 1.0346x; 1.0346x over previous
//
#include <hip/hip_runtime.h>

typedef unsigned int u32;
typedef unsigned short u16;

#define NT 128
#define NBLK 2500

typedef __attribute__((ext_vector_type(8))) short bh8;
typedef __attribute__((ext_vector_type(4))) float f4;
union U8 { uint4 u; bh8 h; };

__device__ __forceinline__ u16 fb(float x){            // fp32->bf16 RNE (used by prep)
    u32 u = __float_as_uint(x);
    u += 0x7fffu + ((u>>16)&1u);
    return (u16)(u>>16);
}
// pack two f32 -> two bf16 in one VALU op (RNE, same as fb): lo=a, hi=b
__device__ __forceinline__ u32 pk2(float a, float b){
    u32 r;
    __asm__("v_cvt_pk_bf16_f32 %0, %1, %2" : "=v"(r) : "v"(a), "v"(b));
    return r;
}
__device__ __forceinline__ float bf_lo(u32 w){ return __uint_as_float(w<<16); }
__device__ __forceinline__ float bf_hi(u32 w){ return __uint_as_float(w & 0xffff0000u); }

// tanh-form gelu (R7/R8 verified): ~10 VALU + 2 trans; deviation from
// erf-form <= ~4e-4, under the bf16 quantization applied right after.
__device__ __forceinline__ float gelu(float x){
    float x2 = x*x;
    float y  = x * fmaf(0.0356774081f, x2, 0.7978845608f);  // sqrt(2/pi)(x+0.044715x^3)
    float t  = __expf(-2.0f * fabsf(y));                    // e^{-2|y|}
    float r  = __builtin_amdgcn_rcpf(1.0f + t);             // raw v_rcp_f32 (~1ulp)
    float m  = t * r;
    float th = fmaf(-2.0f, m, 1.0f);                        // tanh(|y|)
    float hx = 0.5f * x;
    return fmaf(fabsf(hx), th, hx);                         // 0.5x + 0.5|x|tanh(|y|)
}

// ---------- prep: pack W1^T / W2^T (k and v) into MFMA A-frag order, bf16 ----
// ws16 layout (u16): [A1K:2048][A1V:2048][A2K:16384][A2V:16384]
__global__ void prep_pack(const float* __restrict__ kw1, const float* __restrict__ vw1,
                          const float* __restrict__ kw2, const float* __restrict__ vw2,
                          u16* __restrict__ ws16)
{
    int t = blockIdx.x*256 + threadIdx.x;        // 0..36863
    if (t >= 36864) return;
    float val;
    if (t < 4096){
        const float* w1 = (t < 2048) ? kw1 : vw1;
        int u = t & 2047;
        int mt = u >> 9, lane = (u>>3)&63, j = u&7;
        int m = mt*16 + (lane&15);
        int x = (lane>>4)*8 + j;
        val = w1[x*64 + m];
    } else {
        int s2 = t - 4096;
        const float* w2 = (s2 < 16384) ? kw2 : vw2;
        int u = s2 & 16383;
        int blkidx = u >> 9;                      // mt*2+s
        int mt = blkidx >> 1, s = blkidx & 1;
        int lane = (u>>3)&63, j = u&7;
        int ij = mt*16 + (lane&15);
        int c  = s*32 + (lane>>4)*8 + j;
        val = w2[c*256 + ij];
    }
    ws16[t] = fb(val);
}

// ---------- one radial conv via MFMA: t2[16] stays in registers ------------
// FINAL (R15-verified, 94us kernel / 206.8us bench): edge tiles in 2 PAIRS
// (nt = ntp*2+b), both staged via LDS h-bounce into disjoint 1152-u16 hT
// halves before one lgkm fence; A2/b2g read 2x per conv; tm loads hoisted.
// Session-falsified alternatives: nt-serial (R3, slower), in-wave K/V merge
// (R6), register-only staging (R9), permlane reduce (R13/R14 wrong results),
// cross-wave K/V split (R16: correct but 3 blocks/CU < 4 -> net slower).
// Invariants:
//  - every loop indexing a register array MUST fully unroll;
//  - t2v is written UNCONDITIONALLY via selects (v_cndmask), never under a
//    divergent `if`.
__device__ __forceinline__ void conv_mfma(
    const u16* __restrict__ pA1, const u16* __restrict__ pA2,
    const float* __restrict__ b1g, const float* __restrict__ b2g,
    const bh8* __restrict__ B1f,          // [4] cached ef frags
    const u32* __restrict__ tmpS,         // stride 10 u32 rows (16 bf16)
    u16* __restrict__ hT,                 // this wave's H region: 2 tiles x 1152 u16
    float* __restrict__ t2v,              // [16] regs out
    int w, int lane)
{
    const int r = lane & 15, q = lane >> 4;

    #pragma unroll
    for (int mt=0; mt<16; ++mt) t2v[mt] = 0.f;

    // hoisted W1-bias rows
    float4 bva0 = *(const float4*)(b1g +  0 + q*4);
    float4 bva1 = *(const float4*)(b1g + 16 + q*4);
    float4 bva2 = *(const float4*)(b1g + 32 + q*4);
    float4 bva3 = *(const float4*)(b1g + 48 + q*4);

    // hoisted tm loads (all 4 edge tiles) — gated only by phase-0 fence
    uint2 tpA = *(const uint2*)(tmpS + (((w*4+0)*16 + r)*10) + q*2);
    uint2 tpB = *(const uint2*)(tmpS + (((w*4+1)*16 + r)*10) + q*2);
    uint2 tpC = *(const uint2*)(tmpS + (((w*4+2)*16 + r)*10) + q*2);
    uint2 tpD = *(const uint2*)(tmpS + (((w*4+3)*16 + r)*10) + q*2);

    #pragma unroll
    for (int ntp=0; ntp<2; ++ntp){
        bh8 b2f0[2], b2f1[2];
        float tm[2][4];
        {
            uint2 t0 = (ntp==0) ? tpA : tpC;   // folds at compile time
            uint2 t1 = (ntp==0) ? tpB : tpD;
            tm[0][0]=bf_lo(t0.x); tm[0][1]=bf_hi(t0.x);
            tm[0][2]=bf_lo(t0.y); tm[0][3]=bf_hi(t0.y);
            tm[1][0]=bf_lo(t1.x); tm[1][1]=bf_hi(t1.x);
            tm[1][2]=bf_lo(t1.y); tm[1][3]=bf_hi(t1.y);
        }

        // ---- staging: both tiles of the pair -> disjoint hT halves ----
        #pragma unroll
        for (int b=0; b<2; ++b){
            const int nt = ntp*2 + b;
            #pragma unroll
            for (int mt=0; mt<4; ++mt){
                bh8 a1 = *(const bh8*)(pA1 + ((mt*64 + lane)<<3));
                f4 d1 = {0.f,0.f,0.f,0.f};
                d1 = __builtin_amdgcn_mfma_f32_16x16x32_bf16(a1, B1f[nt], d1, 0,0,0);
                float4 bv = (mt==0)?bva0:(mt==1)?bva1:(mt==2)?bva2:bva3;
                float g0 = gelu(d1[0]+bv.x), g1 = gelu(d1[1]+bv.y);
                float g2 = gelu(d1[2]+bv.z), g3 = gelu(d1[3]+bv.w);
                uint2 pk; pk.x = pk2(g0,g1); pk.y = pk2(g2,g3);
                *(uint2*)(hT + b*1152 + r*72 + mt*16 + q*4) = pk;
            }
        }
        // write -> cross-lane-read fence (semantically required)
        __asm__ volatile("s_waitcnt lgkmcnt(0)" ::: "memory");
        #pragma unroll
        for (int b=0; b<2; ++b){
            b2f0[b] = *(const bh8*)(hT + b*1152 + r*72 +      q*8);   // chans q*8..+7
            b2f1[b] = *(const bh8*)(hT + b*1152 + r*72 + 32 + q*8);   // chans 32+q*8..+7
        }

        // ---- main: all 16 ij-tiles, both pair tiles inner ----
        #pragma unroll
        for (int mt=0; mt<16; ++mt){
            bh8 a2s0 = *(const bh8*)(pA2 + (((mt*2+0)*64 + lane)<<3));
            bh8 a2s1 = *(const bh8*)(pA2 + (((mt*2+1)*64 + lane)<<3));
            float4 bv = *(const float4*)(b2g + mt*16 + q*4);
            float pb0, pb1;
            {
                f4 acc = {0.f,0.f,0.f,0.f};
                acc = __builtin_amdgcn_mfma_f32_16x16x32_bf16(a2s0, b2f0[0], acc, 0,0,0);
                acc = __builtin_amdgcn_mfma_f32_16x16x32_bf16(a2s1, b2f1[0], acc, 0,0,0);
                float p = (acc[0]+bv.x)*tm[0][0] + (acc[1]+bv.y)*tm[0][1]
                        + (acc[2]+bv.z)*tm[0][2] + (acc[3]+bv.w)*tm[0][3];
                p += __shfl_xor(p, 16);
                p += __shfl_xor(p, 32);
                pb0 = p;
            }
            {
                f4 acc = {0.f,0.f,0.f,0.f};
                acc = __builtin_amdgcn_mfma_f32_16x16x32_bf16(a2s0, b2f0[1], acc, 0,0,0);
                acc = __builtin_amdgcn_mfma_f32_16x16x32_bf16(a2s1, b2f1[1], acc, 0,0,0);
                float p = (acc[0]+bv.x)*tm[1][0] + (acc[1]+bv.y)*tm[1][1]
                        + (acc[2]+bv.z)*tm[1][2] + (acc[3]+bv.w)*tm[1][3];
                p += __shfl_xor(p, 16);
                p += __shfl_xor(p, 32);
                pb1 = p;
            }
            // owner lane of edge (w*4+nt)*16+r is (q=nt, r); nt = ntp*2 + (q&1)
            float sel = (q & 1) ? pb1 : pb0;
            t2v[mt] = ((q >> 1) == ntp) ? sel : t2v[mt];
        }
    }
}

// ---------------- fused main kernel -------------------------------------------
// FINAL = R15 (verified best: ~94us kernel / 206.8us bench, absmax 9.77e-4).
// Session: 296 -> 207us. Wins: R4 pair-staging (-52us), R8 tanh-gelu +
// parallel softmax + fence cuts (-17us), R10 phase-fold/prefetch hygiene.
// Falsified levers (all measured): occupancy up via LDS cut (R5) or wave
// split (R16), in-wave K/V ILP merge (R6), register-only staging (R9),
// latency hoists beyond R10 (neutral), permlane reduce (R13/R14). Kernel is
// latency-bound (VALU 46%, MFMA 10%, HBM 8%) — a structural plateau of this
// block decomposition, not a HW roofline.
// launch_bounds(128,1): allocator unconstrained (history: arg2=2 capped arch
// VGPRs at 128 -> 950B/thread spill).
__global__ __launch_bounds__(NT, 1) void eqattn_main(
    const float* __restrict__ bk1, const float* __restrict__ bk2,
    const float* __restrict__ bv1, const float* __restrict__ bv2,
    const float* __restrict__ efg, const float* __restrict__ fg,
    const float* __restrict__ qw,  const float* __restrict__ qb,
    const float* __restrict__ kb1, const float* __restrict__ kb2,
    const float* __restrict__ vb1, const float* __restrict__ vb2,
    const float* __restrict__ ow,  const float* __restrict__ ob,
    const int* __restrict__ nidx,  const u16* __restrict__ ws16,
    float* __restrict__ outg)
{
    __shared__ __align__(16) u32 sTmpK[1280];  // 5120: tmp-k bf16 rows (stride 10 u32) -> attn scratch
    __shared__ __align__(16) u32 sTmpV[1280];  // 5120: tmp-v bf16 rows
    __shared__ __align__(16) u32 sKS [2048];   // 8192: k rows 16 u32 (pair-swizzled)
    __shared__ __align__(16) u32 sVS [2048];   // 8192: v rows
    __shared__ __align__(16) u16 sHT [4608];   // 9216: per-wave H regions (2 waves x 2304)
    __shared__ __align__(16) float sQ[264];    // 1056: q vectors [8][33] (written in phase 0)

    const int t    = threadIdx.x;
    const int lane = t & 63;
    const int w    = t >> 6;
    const int r    = lane & 15, q = lane >> 4;
    const int n0   = blockIdx.x * 8;
    const int e    = blockIdx.x * 128 + t;

    const u16* pA1k = ws16;
    const u16* pA1v = ws16 + 2048;
    const u16* pA2k = ws16 + 4096;
    const u16* pA2v = ws16 + 20480;

    // ---- prefetch epilogue coefficients (independent streams) ----
    float4 kc0 = *(const float4*)(bk2 + e*8);
    float4 kc1 = *(const float4*)(bk2 + e*8 + 4);
    float4 vc0 = *(const float4*)(bv2 + e*8);
    float4 vc1 = *(const float4*)(bv2 + e*8 + 4);

    // ---- phase 0: gather f[src], tmpk/tmpv (bf16 rows) ----
    {
        int src = nidx[e];
        const float4* fr = (const float4*)(fg + src*32);
        float fs[32];
        #pragma unroll
        for (int i=0;i<8;++i){
            float4 v = fr[i];
            fs[i*4]=v.x; fs[i*4+1]=v.y; fs[i*4+2]=v.z; fs[i*4+3]=v.w;
        }
        float4 ka = *(const float4*)(bk1+e*8), kbv = *(const float4*)(bk1+e*8+4);
        float4 va = *(const float4*)(bv1+e*8), vbv = *(const float4*)(bv1+e*8+4);
        float b1k[8] = {ka.x,ka.y,ka.z,ka.w,kbv.x,kbv.y,kbv.z,kbv.w};
        float b1v[8] = {va.x,va.y,va.z,va.w,vbv.x,vbv.y,vbv.z,vbv.w};
        float tk[16], tv[16];
        #pragma unroll
        for (int m=0;m<8;++m){
            float t0=0.f,t1=0.f,u0=0.f,u1=0.f;
            #pragma unroll
            for (int d=0;d<4;++d){
                float fv = fs[m*4+d];
                t0 += fv*b1k[d*2];  t1 += fv*b1k[d*2+1];
                u0 += fv*b1v[d*2];  u1 += fv*b1v[d*2+1];
            }
            tk[m*2]=t0; tk[m*2+1]=t1; tv[m*2]=u0; tv[m*2+1]=u1;
        }
        #pragma unroll
        for (int i=0;i<8;++i){
            sTmpK[t*10+i] = pk2(tk[i*2], tk[i*2+1]);
            sTmpV[t*10+i] = pk2(tv[i*2], tv[i*2+1]);
        }
    }

    // ---- q = eq_linear(f, q_w, q_b) in phase 0 (indep of convs) ----
    #pragma unroll 1
    for (int p=0;p<2;++p){
        int task = p*NT + t;
        int ln = task>>5, m=(task>>2)&7, d=task&3;
        const float* frow = fg + (n0+ln)*32;
        int rr = ((d>0)?8:0) + m;
        float acc = (d==0) ? qb[m] : 0.f;
        #pragma unroll
        for (int mm=0;mm<8;++mm) acc += qw[rr*8+mm]*frow[mm*4+d];
        sQ[ln*33 + m*4 + d] = acc;
    }

    // ---- B1 frags: ef rows -> bf16 (shared by K and V convs) ----
    bh8 B1f[4];
    #pragma unroll
    for (int nt=0; nt<4; ++nt){
        int eg = blockIdx.x*128 + (w*4+nt)*16 + r;
        float4 ea = *(const float4*)(efg + eg*32 + q*8);
        float4 eb = *(const float4*)(efg + eg*32 + q*8 + 4);
        U8 uu;
        uu.u.x = pk2(ea.x, ea.y); uu.u.y = pk2(ea.z, ea.w);
        uu.u.z = pk2(eb.x, eb.y); uu.u.w = pk2(eb.z, eb.w);
        B1f[nt] = uu.h;
    }
    // fence: phase-0 sTmp writes (same wave, cross-lane) before tm reads
    __asm__ volatile("s_waitcnt lgkmcnt(0)" ::: "memory");

    u16* hT = sHT + w*2304;

    // ---- K conv ----
    float t2k[16];
    conv_mfma(pA1k, pA2k, kb1, kb2, B1f, sTmpK, hT, t2k, w, lane);
    {
        #pragma unroll
        for (int m=0;m<8;++m){
            float t20 = t2k[2*m], t21 = t2k[2*m+1];
            uint2 pk;
            pk.x = pk2(t20*kc0.x + t21*kc1.x, t20*kc0.y + t21*kc1.y);
            pk.y = pk2(t20*kc0.z + t21*kc1.z, t20*kc0.w + t21*kc1.w);
            *(uint2*)(sKS + t*16 + ((m ^ (t&7))<<1)) = pk;
        }
    }
    // ---- V conv ----
    float t2va[16];
    conv_mfma(pA1v, pA2v, vb1, vb2, B1f, sTmpV, hT, t2va, w, lane);
    {
        #pragma unroll
        for (int m=0;m<8;++m){
            float t20 = t2va[2*m], t21 = t2va[2*m+1];
            uint2 pk;
            pk.x = pk2(t20*vc0.x + t21*vc1.x, t20*vc0.y + t21*vc1.y);
            pk.y = pk2(t20*vc0.z + t21*vc1.z, t20*vc0.w + t21*vc1.w);
            *(uint2*)(sVS + t*16 + ((m ^ (t&7))<<1)) = pk;
        }
    }
    __syncthreads();

    float* lg  = (float*)sTmpK + 264;  // [32][17] = 544 floats (tmp rows dead)
    float* aoS = (float*)sTmpK + 808;  // [8][33] = 264 floats (1072 <= 1280)

    // ---- logits: 512 tasks ----
    #pragma unroll 1
    for (int p=0;p<4;++p){
        int task = p*NT + t;
        int ln = task>>6, hh=(task>>4)&3, k=task&15;
        int row = ln*16 + k;
        const float* qr = sQ + ln*33 + hh*8;
        uint2 k0 = *(const uint2*)(sKS + row*16 + (((hh<<1)     ^ (row&7))<<1));
        uint2 k1 = *(const uint2*)(sKS + row*16 + ((((hh<<1)|1) ^ (row&7))<<1));
        float acc = qr[0]*bf_lo(k0.x)+qr[1]*bf_hi(k0.x)
                  + qr[2]*bf_lo(k0.y)+qr[3]*bf_hi(k0.y)
                  + qr[4]*bf_lo(k1.x)+qr[5]*bf_hi(k1.x)
                  + qr[6]*bf_lo(k1.y)+qr[7]*bf_hi(k1.y);
        lg[(ln*4+hh)*17 + k] = acc * 0.35355339059327373f;
    }
    __syncthreads();

    // ---- softmax over 16 neighbors: parallel (4 lanes/row, all 128 threads;
    // shfl groups stay inside one wave) ----
    {
        int row = t >> 2, sub = t & 3;
        float* rp = lg + row*17 + sub*4;
        float a0=rp[0], a1=rp[1], a2=rp[2], a3=rp[3];
        float mx = fmaxf(fmaxf(a0,a1), fmaxf(a2,a3));
        mx = fmaxf(mx, __shfl_xor(mx, 1));
        mx = fmaxf(mx, __shfl_xor(mx, 2));
        float e0=__expf(a0-mx), e1=__expf(a1-mx);
        float e2=__expf(a2-mx), e3=__expf(a3-mx);
        float s = (e0+e1)+(e2+e3);
        s += __shfl_xor(s, 1);
        s += __shfl_xor(s, 2);
        float inv = __builtin_amdgcn_rcpf(s);
        // one Newton step to keep softmax normalization at fp32 accuracy
        inv = inv * (2.0f - s*inv);
        rp[0]=e0*inv; rp[1]=e1*inv; rp[2]=e2*inv; rp[3]=e3*inv;
    }
    __syncthreads();

    // ---- attention output: 256 tasks ----
    #pragma unroll 1
    for (int p=0;p<2;++p){
        int task = p*NT + t;
        int ln = task>>5, comp = task&31, hh = comp>>3;
        const float* ar = lg + (ln*4+hh)*17;
        float acc=0.f;
        #pragma unroll
        for (int k=0;k<16;++k){
            int row = ln*16 + k;
            u32 wv = sVS[row*16 + (((comp>>2) ^ (row&7))<<1) + ((comp>>1)&1)];
            acc += ar[k] * ((comp&1) ? bf_hi(wv) : bf_lo(wv));
        }
        aoS[ln*33 + comp] = acc;
    }
    __syncthreads();

    // ---- final eq_linear(o_w, o_b) -> fp32 out ----
    #pragma unroll 1
    for (int p=0;p<2;++p){
        int task = p*NT + t;
        int ln = task>>5, m=(task>>2)&7, d=task&3;
        int rr = ((d>0)?8:0) + m;
        float acc = (d==0) ? ob[m] : 0.f;
        #pragma unroll
        for (int mm=0;mm<8;++mm) acc += ow[rr*8+mm]*aoS[ln*33 + mm*4 + d];
        outg[(n0+ln)*32 + m*4 + d] = acc;
    }
}

extern "C" void kernel_launch(void* const* d_in, const int* in_sizes, int n_in,
                              void* d_out, int out_size, void* d_ws, size_t ws_size,
                              hipStream_t stream)
{
    (void)in_sizes; (void)n_in; (void)out_size; (void)ws_size;
    const float* bk1 = (const float*)d_in[0];
    const float* bk2 = (const float*)d_in[1];
    const float* bv1 = (const float*)d_in[2];
    const float* bv2 = (const float*)d_in[3];
    const float* efg = (const float*)d_in[4];
    const float* fg  = (const float*)d_in[5];
    const float* qw  = (const float*)d_in[6];
    const float* qb  = (const float*)d_in[7];
    const float* kw1 = (const float*)d_in[8];
    const float* kb1 = (const float*)d_in[9];
    const float* kw2 = (const float*)d_in[10];
    const float* kb2 = (const float*)d_in[11];
    const float* vw1 = (const float*)d_in[12];
    const float* vb1 = (const float*)d_in[13];
    const float* vw2 = (const float*)d_in[14];
    const float* vb2 = (const float*)d_in[15];
    const float* ow  = (const float*)d_in[16];
    const float* ob  = (const float*)d_in[17];
    const int* nidx  = (const int*)d_in[18];
    u16* ws16 = (u16*)d_ws;

    prep_pack<<<144, 256, 0, stream>>>(kw1, vw1, kw2, vw2, ws16);
    eqattn_main<<<NBLK, NT, 0, stream>>>(
        bk1,bk2,bv1,bv2, efg, fg, qw,qb, kb1,kb2, vb1,vb2,
        ow,ob, nidx, ws16, (float*)d_out);
}